// Round 1
// baseline (565.877 us; speedup 1.0000x reference)
//
#include <hip/hip_runtime.h>
#include <stdint.h>

#define D_MODEL 1024
#define NUM_HEADS 16
#define D_FF 4096
#define BB 2
#define TT 2048
#define NROWS (BB * TT)  // 4096

typedef __bf16 bf16x8 __attribute__((ext_vector_type(8)));
typedef short s16x8 __attribute__((ext_vector_type(8)));
typedef float f32x4 __attribute__((ext_vector_type(4)));

static __device__ __forceinline__ f32x4 mfma16(s16x8 a, s16x8 b, f32x4 c) {
  return __builtin_amdgcn_mfma_f32_16x16x32_bf16(
      __builtin_bit_cast(bf16x8, a), __builtin_bit_cast(bf16x8, b), c, 0, 0, 0);
}

// fp32 -> bf16 RNE, bit-level (avoids header API differences)
static __device__ __forceinline__ short f2b(float f) {
  union { float f; uint32_t u; } v; v.f = f;
  return (short)((v.u + 0x7FFFu + ((v.u >> 16) & 1u)) >> 16);
}

// ---------------- RMSNorm: f32 [rows][1024] -> bf16 ----------------
__global__ __launch_bounds__(256) void rmsnorm_kernel(
    const float* __restrict__ x, const float* __restrict__ g, short* __restrict__ out) {
  const int row = blockIdx.x;
  const int tid = threadIdx.x;
  const float4 xv = *(const float4*)(x + (size_t)row * D_MODEL + tid * 4);
  float ss = xv.x * xv.x + xv.y * xv.y + xv.z * xv.z + xv.w * xv.w;
#pragma unroll
  for (int off = 32; off >= 1; off >>= 1) ss += __shfl_down(ss, off);
  __shared__ float part[4];
  if ((tid & 63) == 0) part[tid >> 6] = ss;
  __syncthreads();
  const float tot = part[0] + part[1] + part[2] + part[3];
  const float sc = rsqrtf(tot * (1.0f / D_MODEL) + 1e-5f);
  const float4 gv = *(const float4*)(g + tid * 4);
  short4 o;
  o.x = f2b(xv.x * sc * gv.x);
  o.y = f2b(xv.y * sc * gv.y);
  o.z = f2b(xv.z * sc * gv.z);
  o.w = f2b(xv.w * sc * gv.w);
  *(short4*)(out + (size_t)row * D_MODEL + tid * 4) = o;
}

// ---------------- f32 -> bf16 convert ----------------
__global__ __launch_bounds__(256) void cvt_kernel(
    const float* __restrict__ in, short* __restrict__ out, int n) {
  const int i = (blockIdx.x * 256 + threadIdx.x) * 8;
  if (i >= n) return;
  const float4 a = *(const float4*)(in + i);
  const float4 b = *(const float4*)(in + i + 4);
  union { short s[8]; s16x8 v; } u;
  u.s[0] = f2b(a.x); u.s[1] = f2b(a.y); u.s[2] = f2b(a.z); u.s[3] = f2b(a.w);
  u.s[4] = f2b(b.x); u.s[5] = f2b(b.y); u.s[6] = f2b(b.z); u.s[7] = f2b(b.w);
  *(s16x8*)(out + i) = u.v;
}

// ---------------- GEMM: C[M,N] = A[M,K] @ B[N,K]^T (both bf16 row-major) ----
// MODE 0: write bf16 C
// MODE 1: write bf16 V-transposed: out[((b*16+h)*64+d)*2048 + t]
// MODE 2: write f32 C + resid
// MODE 3: write bf16 gelu(C)
template <int MODE>
__global__ __launch_bounds__(256) void gemm_bt(
    const short* __restrict__ A, const short* __restrict__ Bw,
    short* __restrict__ outb, float* __restrict__ outf,
    const float* __restrict__ resid, int M, int N, int K) {
  __shared__ __align__(16) short As[128][32];
  __shared__ __align__(16) short Bs[128][32];
  const int tid = threadIdx.x;
  const int lane = tid & 63;
  const int w = tid >> 6, wr = w >> 1, wc = w & 1;
  const int l15 = lane & 15, lg = lane >> 4;
  const int brow = blockIdx.y * 128, bcol = blockIdx.x * 128;

  f32x4 acc[4][4] = {};

  const int sr = tid >> 1;          // LDS row this thread stages (0..127)
  const int sc0 = (tid & 1) * 2;    // first of two 8-elem chunks (0..3)
  const int swW = (sr >> 1) & 3;    // write-side XOR swizzle
  const short* Ap = A + (size_t)(brow + sr) * K + sc0 * 8;
  const short* Bp = Bw + (size_t)(bcol + sr) * K + sc0 * 8;

  for (int k0 = 0; k0 < K; k0 += 32) {
    const s16x8 a0 = *(const s16x8*)(Ap);
    const s16x8 a1 = *(const s16x8*)(Ap + 8);
    const s16x8 b0 = *(const s16x8*)(Bp);
    const s16x8 b1 = *(const s16x8*)(Bp + 8);
    Ap += 32; Bp += 32;
    __syncthreads();  // previous iteration's reads complete
    *(s16x8*)&As[sr][(sc0 ^ swW) * 8] = a0;
    *(s16x8*)&As[sr][((sc0 + 1) ^ swW) * 8] = a1;
    *(s16x8*)&Bs[sr][(sc0 ^ swW) * 8] = b0;
    *(s16x8*)&Bs[sr][((sc0 + 1) ^ swW) * 8] = b1;
    __syncthreads();
    s16x8 af[4], bf[4];
#pragma unroll
    for (int m = 0; m < 4; ++m) {
      const int r = wr * 64 + m * 16 + l15;
      af[m] = *(const s16x8*)&As[r][(lg ^ ((r >> 1) & 3)) * 8];
    }
#pragma unroll
    for (int n = 0; n < 4; ++n) {
      const int r = wc * 64 + n * 16 + l15;
      bf[n] = *(const s16x8*)&Bs[r][(lg ^ ((r >> 1) & 3)) * 8];
    }
#pragma unroll
    for (int m = 0; m < 4; ++m)
#pragma unroll
      for (int n = 0; n < 4; ++n)
        acc[m][n] = mfma16(af[m], bf[n], acc[m][n]);
  }

#pragma unroll
  for (int m = 0; m < 4; ++m)
#pragma unroll
    for (int n = 0; n < 4; ++n)
#pragma unroll
      for (int r = 0; r < 4; ++r) {
        const int grow = brow + wr * 64 + m * 16 + lg * 4 + r;
        const int gcol = bcol + wc * 64 + n * 16 + l15;
        const float v = acc[m][n][r];
        const size_t idx = (size_t)grow * N + gcol;
        if (MODE == 0) {
          outb[idx] = f2b(v);
        } else if (MODE == 1) {
          const int bq = grow >> 11, t = grow & 2047;
          const int hh = gcol >> 6, d = gcol & 63;
          outb[(((size_t)((bq << 4) + hh) << 6) + d) * 2048 + t] = f2b(v);
        } else if (MODE == 2) {
          outf[idx] = v + resid[idx];
        } else {
          const float gl = 0.5f * v * (1.0f + erff(v * 0.70710678118f));
          outb[idx] = f2b(gl);
        }
      }
}

// ---------------- Flash-style causal attention ----------------
// q,k: bf16 [b*2048][1024] (head h at col h*64); v: bf16 [b*16+h][64][2048] (transposed)
// out att: bf16 [b*2048][1024]
__global__ __launch_bounds__(256) void attn_kernel(
    const short* __restrict__ qb, const short* __restrict__ kb,
    const short* __restrict__ vt, short* __restrict__ att) {
  const int bh = blockIdx.y;
  const int bq = bh >> 4, h = bh & 15;
  const int qbase = blockIdx.x * 64;
  const int tid = threadIdx.x, lane = tid & 63, w = tid >> 6;
  const int l15 = lane & 15, lg = lane >> 4;

  __shared__ __align__(16) short Ks[32][64];  // [k][d]
  __shared__ __align__(16) short Vs[64][32];  // [d][k]
  __shared__ __align__(16) short Ps[4][16][32];  // per-wave P tile [q][k]

  const short* qhead = qb + (size_t)bq * 2048 * 1024 + h * 64;
  const short* khead = kb + (size_t)bq * 2048 * 1024 + h * 64;
  const short* vhead = vt + (size_t)bh * 64 * 2048;

  // Q fragments hoisted (wave w owns q rows qbase+w*16 .. +16)
  const int qr = qbase + w * 16 + l15;
  const short* qp = qhead + (size_t)qr * 1024 + lg * 8;
  const s16x8 aq0 = *(const s16x8*)(qp);
  const s16x8 aq1 = *(const s16x8*)(qp + 32);

  f32x4 acc[4] = {};
  float mrow[4] = {-1e30f, -1e30f, -1e30f, -1e30f};
  float lrow[4] = {0.f, 0.f, 0.f, 0.f};

  const int kr = tid >> 3, kc = tid & 7;  // Ks staging: row, chunk
  const int kcw = (kc ^ (kr & 7)) * 8;
  const int vr = tid >> 2, vc = tid & 3;  // Vs staging: row(d), chunk
  const int vcw = (vc ^ ((vr >> 1) & 3)) * 8;

  const int ktiles = qbase / 32 + 2;
  for (int kt = 0; kt < ktiles; ++kt) {
    const int k0 = kt * 32;
    const s16x8 kv = *(const s16x8*)(khead + (size_t)(k0 + kr) * 1024 + kc * 8);
    const s16x8 vv = *(const s16x8*)(vhead + (size_t)vr * 2048 + k0 + vc * 8);
    __syncthreads();
    *(s16x8*)&Ks[kr][kcw] = kv;
    *(s16x8*)&Vs[vr][vcw] = vv;
    __syncthreads();

    // S = Q K^T  (2 col-fragments x 2 d-halves)
    f32x4 s[2] = {};
#pragma unroll
    for (int c = 0; c < 2; ++c) {
      const int r = c * 16 + l15;
      const int sw = r & 7;
      const s16x8 bk0 = *(const s16x8*)&Ks[r][((0 + lg) ^ sw) * 8];
      const s16x8 bk1 = *(const s16x8*)&Ks[r][((4 + lg) ^ sw) * 8];
      s[c] = mfma16(aq0, bk0, s[c]);
      s[c] = mfma16(aq1, bk1, s[c]);
    }
    // scale + causal mask
#pragma unroll
    for (int c = 0; c < 2; ++c)
#pragma unroll
      for (int r = 0; r < 4; ++r) {
        const int qrow = qbase + w * 16 + lg * 4 + r;
        const int kcol = k0 + c * 16 + l15;
        const float v = s[c][r] * 0.125f;
        s[c][r] = (kcol > qrow) ? -1e30f : v;
      }
    // online softmax: row stats live across 16 lanes sharing lg
    float mt[4], rs[4], scl[4];
#pragma unroll
    for (int r = 0; r < 4; ++r) mt[r] = fmaxf(s[0][r], s[1][r]);
#pragma unroll
    for (int off = 8; off >= 1; off >>= 1)
#pragma unroll
      for (int r = 0; r < 4; ++r) mt[r] = fmaxf(mt[r], __shfl_xor(mt[r], off));
#pragma unroll
    for (int r = 0; r < 4; ++r) {
      const float mnew = fmaxf(mrow[r], mt[r]);
      scl[r] = __expf(mrow[r] - mnew);
      mrow[r] = mnew;
      s[0][r] = __expf(s[0][r] - mnew);
      s[1][r] = __expf(s[1][r] - mnew);
      rs[r] = s[0][r] + s[1][r];
    }
#pragma unroll
    for (int off = 8; off >= 1; off >>= 1)
#pragma unroll
      for (int r = 0; r < 4; ++r) rs[r] += __shfl_xor(rs[r], off);
#pragma unroll
    for (int r = 0; r < 4; ++r) lrow[r] = lrow[r] * scl[r] + rs[r];
#pragma unroll
    for (int df = 0; df < 4; ++df)
#pragma unroll
      for (int r = 0; r < 4; ++r) acc[df][r] *= scl[r];

    // P (C-layout) -> per-wave LDS -> A-fragment layout
#pragma unroll
    for (int c = 0; c < 2; ++c)
#pragma unroll
      for (int r = 0; r < 4; ++r) {
        const int prow = lg * 4 + r;
        const int pcol = c * 16 + l15;
        const int chunk = pcol >> 3;
        Ps[w][prow][((chunk ^ ((prow >> 1) & 3)) << 3) + (pcol & 7)] = f2b(s[c][r]);
      }
    const s16x8 pa = *(const s16x8*)&Ps[w][l15][(lg ^ ((l15 >> 1) & 3)) * 8];
#pragma unroll
    for (int df = 0; df < 4; ++df) {
      const int r = df * 16 + l15;
      const s16x8 bv = *(const s16x8*)&Vs[r][(lg ^ ((r >> 1) & 3)) * 8];
      acc[df] = mfma16(pa, bv, acc[df]);
    }
    __syncthreads();
  }

  float inv[4];
#pragma unroll
  for (int r = 0; r < 4; ++r) inv[r] = 1.0f / lrow[r];
#pragma unroll
  for (int df = 0; df < 4; ++df)
#pragma unroll
    for (int r = 0; r < 4; ++r) {
      const int qrow = qbase + w * 16 + lg * 4 + r;
      const int d = df * 16 + l15;
      att[((size_t)(bq * 2048) + qrow) * 1024 + h * 64 + d] = f2b(acc[df][r] * inv[r]);
    }
}

// ---------------- launch ----------------
extern "C" void kernel_launch(void* const* d_in, const int* in_sizes, int n_in,
                              void* d_out, int out_size, void* d_ws, size_t ws_size,
                              hipStream_t stream) {
  const float* x  = (const float*)d_in[0];
  const float* wq = (const float*)d_in[1];
  const float* wk = (const float*)d_in[2];
  const float* wv = (const float*)d_in[3];
  const float* wo = (const float*)d_in[4];
  const float* w1 = (const float*)d_in[5];
  const float* w2 = (const float*)d_in[6];
  const float* g1 = (const float*)d_in[7];
  const float* g2 = (const float*)d_in[8];
  float* out = (float*)d_out;

  char* ws = (char*)d_ws;
  const size_t MB = 1u << 20;
  short* wq_b  = (short*)(ws + 0 * MB);
  short* wk_b  = (short*)(ws + 2 * MB);
  short* wv_b  = (short*)(ws + 4 * MB);
  short* wo_b  = (short*)(ws + 6 * MB);
  short* w1_b  = (short*)(ws + 8 * MB);
  short* w2_b  = (short*)(ws + 16 * MB);
  short* xn_b  = (short*)(ws + 24 * MB);
  short* q_b   = (short*)(ws + 32 * MB);
  short* k_b   = (short*)(ws + 40 * MB);
  short* vt_b  = (short*)(ws + 48 * MB);
  short* att_b = (short*)(ws + 56 * MB);
  short* gel_b = (short*)(ws + 32 * MB);  // aliases q/k/vt/att (dead by FFN1)

  // 1. xn = rmsnorm(x, g1) -> bf16
  rmsnorm_kernel<<<NROWS, 256, 0, stream>>>(x, g1, xn_b);
  // 2. weights -> bf16
  cvt_kernel<<<512, 256, 0, stream>>>(wq, wq_b, 1 << 20);
  cvt_kernel<<<512, 256, 0, stream>>>(wk, wk_b, 1 << 20);
  cvt_kernel<<<512, 256, 0, stream>>>(wv, wv_b, 1 << 20);
  cvt_kernel<<<512, 256, 0, stream>>>(wo, wo_b, 1 << 20);
  cvt_kernel<<<2048, 256, 0, stream>>>(w1, w1_b, 1 << 22);
  cvt_kernel<<<2048, 256, 0, stream>>>(w2, w2_b, 1 << 22);

  const dim3 gN1024(8, 32);   // N=1024, M=4096
  const dim3 gN4096(32, 32);  // N=4096, M=4096
  // 3. Q, K, V
  gemm_bt<0><<<gN1024, 256, 0, stream>>>(xn_b, wq_b, q_b, nullptr, nullptr, NROWS, 1024, 1024);
  gemm_bt<0><<<gN1024, 256, 0, stream>>>(xn_b, wk_b, k_b, nullptr, nullptr, NROWS, 1024, 1024);
  gemm_bt<1><<<gN1024, 256, 0, stream>>>(xn_b, wv_b, vt_b, nullptr, nullptr, NROWS, 1024, 1024);
  // 4. attention
  attn_kernel<<<dim3(TT / 64, 32), 256, 0, stream>>>(q_b, k_b, vt_b, att_b);
  // 5. x1 = x + att @ wo^T   (x1 lives in d_out)
  gemm_bt<2><<<gN1024, 256, 0, stream>>>(att_b, wo_b, nullptr, out, x, NROWS, 1024, 1024);
  // 6. h = rmsnorm(x1, g2) -> bf16
  rmsnorm_kernel<<<NROWS, 256, 0, stream>>>(out, g2, xn_b);
  // 7. g = gelu(h @ w1^T) -> bf16
  gemm_bt<3><<<gN4096, 256, 0, stream>>>(xn_b, w1_b, gel_b, nullptr, nullptr, NROWS, 4096, 1024);
  // 8. out = x1 + g @ w2^T
  gemm_bt<2><<<gN1024, 256, 0, stream>>>(gel_b, w2_b, nullptr, out, out, NROWS, 1024, 4096);
}

// Round 2
// 463.070 us; speedup vs baseline: 1.2220x; 1.2220x over previous
//
#include <hip/hip_runtime.h>
#include <stdint.h>

#define D_MODEL 1024
#define NUM_HEADS 16
#define D_FF 4096
#define BB 2
#define TT 2048
#define NROWS (BB * TT)  // 4096

typedef __bf16 bf16x8 __attribute__((ext_vector_type(8)));
typedef short s16x8 __attribute__((ext_vector_type(8)));
typedef float f32x4 __attribute__((ext_vector_type(4)));

static __device__ __forceinline__ f32x4 mfma16(s16x8 a, s16x8 b, f32x4 c) {
  return __builtin_amdgcn_mfma_f32_16x16x32_bf16(
      __builtin_bit_cast(bf16x8, a), __builtin_bit_cast(bf16x8, b), c, 0, 0, 0);
}

// fp32 -> bf16 RNE
static __device__ __forceinline__ short f2b(float f) {
  union { float f; uint32_t u; } v; v.f = f;
  return (short)((v.u + 0x7FFFu + ((v.u >> 16) & 1u)) >> 16);
}

typedef __attribute__((address_space(1))) const unsigned int gu32;
typedef __attribute__((address_space(3))) unsigned int lu32;
static __device__ __forceinline__ void gload16(const short* g, short* l) {
  // 16B per lane, LDS dest = wave-uniform base + lane*16
  __builtin_amdgcn_global_load_lds((gu32*)g, (lu32*)l, 16, 0, 0);
}

// ---------------- RMSNorm: f32 [rows][1024] -> bf16 ----------------
__global__ __launch_bounds__(256) void rmsnorm_kernel(
    const float* __restrict__ x, const float* __restrict__ g, short* __restrict__ out) {
  const int row = blockIdx.x;
  const int tid = threadIdx.x;
  const float4 xv = *(const float4*)(x + (size_t)row * D_MODEL + tid * 4);
  float ss = xv.x * xv.x + xv.y * xv.y + xv.z * xv.z + xv.w * xv.w;
#pragma unroll
  for (int off = 32; off >= 1; off >>= 1) ss += __shfl_down(ss, off);
  __shared__ float part[4];
  if ((tid & 63) == 0) part[tid >> 6] = ss;
  __syncthreads();
  const float tot = part[0] + part[1] + part[2] + part[3];
  const float sc = rsqrtf(tot * (1.0f / D_MODEL) + 1e-5f);
  const float4 gv = *(const float4*)(g + tid * 4);
  short4 o;
  o.x = f2b(xv.x * sc * gv.x);
  o.y = f2b(xv.y * sc * gv.y);
  o.z = f2b(xv.z * sc * gv.z);
  o.w = f2b(xv.w * sc * gv.w);
  *(short4*)(out + (size_t)row * D_MODEL + tid * 4) = o;
}

// ---------------- f32 -> bf16 converts ----------------
__global__ __launch_bounds__(256) void cvt_kernel(
    const float* __restrict__ in, short* __restrict__ out, int n) {
  const int i = (blockIdx.x * 256 + threadIdx.x) * 8;
  if (i >= n) return;
  const float4 a = *(const float4*)(in + i);
  const float4 b = *(const float4*)(in + i + 4);
  union { short s[8]; s16x8 v; } u;
  u.s[0] = f2b(a.x); u.s[1] = f2b(a.y); u.s[2] = f2b(a.z); u.s[3] = f2b(a.w);
  u.s[4] = f2b(b.x); u.s[5] = f2b(b.y); u.s[6] = f2b(b.z); u.s[7] = f2b(b.w);
  *(s16x8*)(out + i) = u.v;
}

__global__ __launch_bounds__(256) void cvt4_kernel(
    const float* __restrict__ a, const float* __restrict__ b,
    const float* __restrict__ c, const float* __restrict__ d,
    short* __restrict__ oa, short* __restrict__ ob,
    short* __restrict__ oc, short* __restrict__ od) {
  const int gid = blockIdx.x * 256 + threadIdx.x;
  const int seg = gid >> 17;           // 131072 threads per 1M-elem weight
  const int off = (gid & 131071) * 8;
  const float* in = seg == 0 ? a : seg == 1 ? b : seg == 2 ? c : d;
  short* out = seg == 0 ? oa : seg == 1 ? ob : seg == 2 ? oc : od;
  const float4 lo = *(const float4*)(in + off);
  const float4 hi = *(const float4*)(in + off + 4);
  union { short s[8]; s16x8 v; } u;
  u.s[0] = f2b(lo.x); u.s[1] = f2b(lo.y); u.s[2] = f2b(lo.z); u.s[3] = f2b(lo.w);
  u.s[4] = f2b(hi.x); u.s[5] = f2b(hi.y); u.s[6] = f2b(hi.z); u.s[7] = f2b(hi.w);
  *(s16x8*)(out + off) = u.v;
}

// ---------------- GEMM core: m97 structure ----------------
// C[M,N] = A[M,K] @ B[N,K]^T, bf16 in, fp32 acc. BM = MFRAG*32, BN = 128.
// Linear LDS [rows][32] (64-B rows -> b128 frag reads at structural floor),
// global_load_lds width 16, 2-barrier K-loop.
template <int MFRAG>
__device__ __forceinline__ void gemm_core(
    const short* __restrict__ A, const short* __restrict__ Bw,
    int K, int brow, int bcol, short (*As)[32], short (*Bs)[32],
    f32x4 (*acc)[4]) {
  const int tid = threadIdx.x;
  const int lane = tid & 63, wv = tid >> 6;
  const int l15 = lane & 15, lg = lane >> 4;
  const int wr = wv >> 1, wc = wv & 1;

  const int srow = wv * 16 + (lane >> 2);  // + j*64
  const int schunk = lane & 3;
  const short* Ag[MFRAG / 2];
  const short* Bg[2];
  short* Al[MFRAG / 2];
  short* Bl[2];
#pragma unroll
  for (int j = 0; j < MFRAG / 2; ++j) {
    Ag[j] = A + (size_t)(brow + j * 64 + srow) * K + schunk * 8;
    Al[j] = &As[0][0] + j * 2048 + wv * 512;
  }
#pragma unroll
  for (int j = 0; j < 2; ++j) {
    Bg[j] = Bw + (size_t)(bcol + j * 64 + srow) * K + schunk * 8;
    Bl[j] = &Bs[0][0] + j * 2048 + wv * 512;
  }

  for (int k0 = 0; k0 < K; k0 += 32) {
    __syncthreads();  // all waves done reading previous tile
#pragma unroll
    for (int j = 0; j < MFRAG / 2; ++j) { gload16(Ag[j], Al[j]); Ag[j] += 32; }
#pragma unroll
    for (int j = 0; j < 2; ++j) { gload16(Bg[j], Bl[j]); Bg[j] += 32; }
    __syncthreads();  // vmcnt drained -> tile ready
    s16x8 af[MFRAG], bfr[4];
#pragma unroll
    for (int m = 0; m < MFRAG; ++m)
      af[m] = *(const s16x8*)&As[wr * (MFRAG * 16) + m * 16 + l15][lg * 8];
#pragma unroll
    for (int n = 0; n < 4; ++n)
      bfr[n] = *(const s16x8*)&Bs[wc * 64 + n * 16 + l15][lg * 8];
#pragma unroll
    for (int m = 0; m < MFRAG; ++m)
#pragma unroll
      for (int n = 0; n < 4; ++n)
        acc[m][n] = mfma16(af[m], bfr[n], acc[m][n]);
  }
}

// MODE 0: bf16 C. MODE 2: f32 C + resid. MODE 3: bf16 gelu(C).
template <int MODE, int MFRAG>
__global__ __launch_bounds__(256) void gemm_bt(
    const short* __restrict__ A, const short* __restrict__ Bw,
    short* __restrict__ outb, float* __restrict__ outf,
    const float* __restrict__ resid, int K, int N) {
  __shared__ __align__(16) short As[MFRAG * 32][32];
  __shared__ __align__(16) short Bs[128][32];
  f32x4 acc[MFRAG][4] = {};
  const int brow = blockIdx.y * (MFRAG * 32), bcol = blockIdx.x * 128;
  gemm_core<MFRAG>(A, Bw, K, brow, bcol, As, Bs, acc);

  const int tid = threadIdx.x, lane = tid & 63;
  const int wv = tid >> 6, wr = wv >> 1, wc = wv & 1;
  const int l15 = lane & 15, lg = lane >> 4;
#pragma unroll
  for (int m = 0; m < MFRAG; ++m)
#pragma unroll
    for (int n = 0; n < 4; ++n)
#pragma unroll
      for (int r = 0; r < 4; ++r) {
        const int grow = brow + wr * (MFRAG * 16) + m * 16 + lg * 4 + r;
        const int gcol = bcol + wc * 64 + n * 16 + l15;
        const float v = acc[m][n][r];
        const size_t idx = (size_t)grow * N + gcol;
        if (MODE == 0) {
          outb[idx] = f2b(v);
        } else if (MODE == 2) {
          outf[idx] = v + resid[idx];
        } else {
          outb[idx] = f2b(0.5f * v * (1.0f + erff(v * 0.70710678118f)));
        }
      }
}

// Fused QKV: grid.x = 24 (8 col-blocks x 3 weights), grid.y = 32 row-blocks.
// sel 0->Q, 1->K, 2->V (V written transposed [bh][d][t]).
__global__ __launch_bounds__(256) void gemm_qkv(
    const short* __restrict__ A, const short* __restrict__ Wq,
    const short* __restrict__ Wk, const short* __restrict__ Wv,
    short* __restrict__ qout, short* __restrict__ kout, short* __restrict__ vtout) {
  __shared__ __align__(16) short As[128][32];
  __shared__ __align__(16) short Bs[128][32];
  const int sel = blockIdx.x >> 3;
  const int bcol = (blockIdx.x & 7) * 128;
  const int brow = blockIdx.y * 128;
  const short* Bw = sel == 0 ? Wq : sel == 1 ? Wk : Wv;
  f32x4 acc[4][4] = {};
  gemm_core<4>(A, Bw, 1024, brow, bcol, As, Bs, acc);

  const int tid = threadIdx.x, lane = tid & 63;
  const int wv = tid >> 6, wr = wv >> 1, wc = wv & 1;
  const int l15 = lane & 15, lg = lane >> 4;
  short* outb = sel == 0 ? qout : kout;
#pragma unroll
  for (int m = 0; m < 4; ++m)
#pragma unroll
    for (int n = 0; n < 4; ++n)
#pragma unroll
      for (int r = 0; r < 4; ++r) {
        const int grow = brow + wr * 64 + m * 16 + lg * 4 + r;
        const int gcol = bcol + wc * 64 + n * 16 + l15;
        const short v = f2b(acc[m][n][r]);
        if (sel < 2) {
          outb[(size_t)grow * 1024 + gcol] = v;
        } else {
          const int bq = grow >> 11, t = grow & 2047;
          const int hh = gcol >> 6, d = gcol & 63;
          vtout[(((size_t)((bq << 4) + hh) << 6) + d) * 2048 + t] = v;
        }
      }
}

// ---------------- Flash-style causal attention, QBLK=128 KBLK=64 ----------
// q,k: bf16 [b*2048][1024]; v: bf16 [b*16+h][64][2048] (transposed); out same as q.
// 4 waves; wave w owns q-rows {qbase+mq*64+w*16+0..15 : mq=0,1}.
__global__ __launch_bounds__(256) void attn_kernel(
    const short* __restrict__ qb, const short* __restrict__ kb,
    const short* __restrict__ vt, short* __restrict__ att) {
  const int bh = blockIdx.y, bq = bh >> 4, h = bh & 15;
  const int qbase = ((int)gridDim.x - 1 - (int)blockIdx.x) * 128;  // heavy first
  const int tid = threadIdx.x, lane = tid & 63, w = tid >> 6;
  const int l15 = lane & 15, lg = lane >> 4;

  __shared__ __align__(16) short Ks[64][64];      // [k][d], chunk-swizzled
  __shared__ __align__(16) short Vs[64][64];      // [d][k], chunk-swizzled
  __shared__ __align__(16) short Ps[4][32][64];   // per-wave P, chunk-swizzled

  const short* qhead = qb + (size_t)bq * 2048 * 1024 + h * 64;
  const short* khead = kb + (size_t)bq * 2048 * 1024 + h * 64;
  const short* vhead = vt + (size_t)bh * 64 * 2048;

  // Q fragments hoisted: aq[mq][kh]
  s16x8 aq[2][2];
#pragma unroll
  for (int mq = 0; mq < 2; ++mq) {
    const short* qp = qhead + (size_t)(qbase + mq * 64 + w * 16 + l15) * 1024 + lg * 8;
    aq[mq][0] = *(const s16x8*)(qp);
    aq[mq][1] = *(const s16x8*)(qp + 32);
  }

  f32x4 acc[2][4] = {};
  float mrow[2][4], lrow[2][4];
#pragma unroll
  for (int mq = 0; mq < 2; ++mq)
#pragma unroll
    for (int r = 0; r < 4; ++r) { mrow[mq][r] = -1e30f; lrow[mq][r] = 0.f; }

  // staging: lane covers LDS bytes base+lane*16; row = j*32 + wv*8 + (lane>>3)
  // source chunk pre-swizzled so swizzled reads see chunk g at slot g^(row&7)
  const int ssub = lane >> 3;                // row&7 for every issue
  const int gch = (lane & 7) ^ ssub;         // global chunk to fetch
  const int swz = l15 & 7;                   // read-side swizzle (row&7 = l15&7)

  const int nkt = qbase / 64 + 2;
  for (int kt = 0; kt < nkt; ++kt) {
    const int k0 = kt * 64;
    __syncthreads();  // all waves done reading previous K/V tile
#pragma unroll
    for (int j = 0; j < 2; ++j) {
      const int row = j * 32 + w * 8 + ssub;
      gload16(khead + (size_t)(k0 + row) * 1024 + gch * 8,
              &Ks[0][0] + j * 2048 + w * 512);
      gload16(vhead + (size_t)row * 2048 + k0 + gch * 8,
              &Vs[0][0] + j * 2048 + w * 512);
    }
    __syncthreads();  // tiles ready

    const bool act0 = (k0 <= qbase + w * 16 + 15);  // frag1 always active

    // K b-fragments (shared across mq)
    s16x8 bk[4][2];
#pragma unroll
    for (int c = 0; c < 4; ++c) {
      const int r = c * 16 + l15;
#pragma unroll
      for (int kh = 0; kh < 2; ++kh)
        bk[c][kh] = *(const s16x8*)&Ks[r][((kh * 4 + lg) ^ swz) * 8];
    }
    // V b-fragments (shared across mq)
    s16x8 bv[4][2];
#pragma unroll
    for (int df = 0; df < 4; ++df) {
      const int r = df * 16 + l15;
#pragma unroll
      for (int kh = 0; kh < 2; ++kh)
        bv[df][kh] = *(const s16x8*)&Vs[r][((kh * 4 + lg) ^ swz) * 8];
    }

#pragma unroll
    for (int mq = 0; mq < 2; ++mq) {
      if (mq == 0 && !act0) continue;
      const int rbase = qbase + mq * 64 + w * 16;  // frag min q-row
      // QK^T
      f32x4 s[4] = {};
#pragma unroll
      for (int c = 0; c < 4; ++c) {
        s[c] = mfma16(aq[mq][0], bk[c][0], s[c]);
        s[c] = mfma16(aq[mq][1], bk[c][1], s[c]);
      }
      // scale (+ causal mask only near diagonal)
      if (k0 + 63 > rbase) {
#pragma unroll
        for (int c = 0; c < 4; ++c) {
          const int kcol = k0 + c * 16 + l15;
#pragma unroll
          for (int r = 0; r < 4; ++r) {
            const float v = s[c][r] * 0.125f;
            s[c][r] = (kcol > rbase + lg * 4 + r) ? -1e30f : v;
          }
        }
      } else {
#pragma unroll
        for (int c = 0; c < 4; ++c)
#pragma unroll
          for (int r = 0; r < 4; ++r) s[c][r] *= 0.125f;
      }
      // online softmax (row stats across the 16 lanes sharing lg)
      float mt[4], rs[4], scl[4];
#pragma unroll
      for (int r = 0; r < 4; ++r)
        mt[r] = fmaxf(fmaxf(s[0][r], s[1][r]), fmaxf(s[2][r], s[3][r]));
#pragma unroll
      for (int off = 8; off >= 1; off >>= 1)
#pragma unroll
        for (int r = 0; r < 4; ++r) mt[r] = fmaxf(mt[r], __shfl_xor(mt[r], off));
#pragma unroll
      for (int r = 0; r < 4; ++r) {
        const float mnew = fmaxf(mrow[mq][r], mt[r]);
        scl[r] = __expf(mrow[mq][r] - mnew);
        mrow[mq][r] = mnew;
        rs[r] = 0.f;
#pragma unroll
        for (int c = 0; c < 4; ++c) {
          s[c][r] = __expf(s[c][r] - mnew);
          rs[r] += s[c][r];
        }
      }
#pragma unroll
      for (int off = 8; off >= 1; off >>= 1)
#pragma unroll
        for (int r = 0; r < 4; ++r) rs[r] += __shfl_xor(rs[r], off);
#pragma unroll
      for (int r = 0; r < 4; ++r) lrow[mq][r] = lrow[mq][r] * scl[r] + rs[r];
#pragma unroll
      for (int df = 0; df < 4; ++df)
#pragma unroll
        for (int r = 0; r < 4; ++r) acc[mq][df][r] *= scl[r];

      // P (C-layout) -> per-wave LDS (chunk-swizzled) -> A-fragments
#pragma unroll
      for (int c = 0; c < 4; ++c)
#pragma unroll
        for (int r = 0; r < 4; ++r) {
          const int prow = mq * 16 + lg * 4 + r;
          const int ch = c * 2 + (l15 >> 3);
          Ps[w][prow][((ch ^ (prow & 7)) << 3) + (l15 & 7)] = f2b(s[c][r]);
        }
#pragma unroll
      for (int kh = 0; kh < 2; ++kh) {
        const s16x8 pa = *(const s16x8*)&Ps[w][mq * 16 + l15][((kh * 4 + lg) ^ swz) * 8];
#pragma unroll
        for (int df = 0; df < 4; ++df)
          acc[mq][df] = mfma16(pa, bv[df][kh], acc[mq][df]);
      }
    }
  }

#pragma unroll
  for (int mq = 0; mq < 2; ++mq) {
    float inv[4];
#pragma unroll
    for (int r = 0; r < 4; ++r) inv[r] = 1.0f / lrow[mq][r];
#pragma unroll
    for (int df = 0; df < 4; ++df)
#pragma unroll
      for (int r = 0; r < 4; ++r) {
        const int qrow = qbase + mq * 64 + w * 16 + lg * 4 + r;
        const int d = df * 16 + l15;
        att[((size_t)(bq * 2048) + qrow) * 1024 + h * 64 + d] =
            f2b(acc[mq][df][r] * inv[r]);
      }
  }
}

// ---------------- launch ----------------
extern "C" void kernel_launch(void* const* d_in, const int* in_sizes, int n_in,
                              void* d_out, int out_size, void* d_ws, size_t ws_size,
                              hipStream_t stream) {
  const float* x  = (const float*)d_in[0];
  const float* wq = (const float*)d_in[1];
  const float* wk = (const float*)d_in[2];
  const float* wv = (const float*)d_in[3];
  const float* wo = (const float*)d_in[4];
  const float* w1 = (const float*)d_in[5];
  const float* w2 = (const float*)d_in[6];
  const float* g1 = (const float*)d_in[7];
  const float* g2 = (const float*)d_in[8];
  float* out = (float*)d_out;

  char* ws = (char*)d_ws;
  const size_t MB = 1u << 20;
  short* wq_b  = (short*)(ws + 0 * MB);
  short* wk_b  = (short*)(ws + 2 * MB);
  short* wv_b  = (short*)(ws + 4 * MB);
  short* wo_b  = (short*)(ws + 6 * MB);
  short* w1_b  = (short*)(ws + 8 * MB);
  short* w2_b  = (short*)(ws + 16 * MB);
  short* xn_b  = (short*)(ws + 24 * MB);
  short* q_b   = (short*)(ws + 32 * MB);
  short* k_b   = (short*)(ws + 40 * MB);
  short* vt_b  = (short*)(ws + 48 * MB);
  short* att_b = (short*)(ws + 56 * MB);
  short* gel_b = (short*)(ws + 32 * MB);  // aliases q/k/vt/att (dead by FFN1)

  // 1. xn = rmsnorm(x, g1)
  rmsnorm_kernel<<<NROWS, 256, 0, stream>>>(x, g1, xn_b);
  // 2. weights -> bf16
  cvt4_kernel<<<2048, 256, 0, stream>>>(wq, wk, wv, wo, wq_b, wk_b, wv_b, wo_b);
  cvt_kernel<<<2048, 256, 0, stream>>>(w1, w1_b, 1 << 22);
  cvt_kernel<<<2048, 256, 0, stream>>>(w2, w2_b, 1 << 22);
  // 3. fused QKV (V transposed)
  gemm_qkv<<<dim3(24, 32), 256, 0, stream>>>(xn_b, wq_b, wk_b, wv_b, q_b, k_b, vt_b);
  // 4. attention
  attn_kernel<<<dim3(TT / 128, 32), 256, 0, stream>>>(q_b, k_b, vt_b, att_b);
  // 5. x1 = x + att @ wo^T  (x1 in d_out, f32)
  gemm_bt<2, 2><<<dim3(8, 64), 256, 0, stream>>>(att_b, wo_b, nullptr, out, x, 1024, 1024);
  // 6. h = rmsnorm(x1, g2)
  rmsnorm_kernel<<<NROWS, 256, 0, stream>>>(out, g2, xn_b);
  // 7. g = gelu(h @ w1^T)
  gemm_bt<3, 4><<<dim3(32, 32), 256, 0, stream>>>(xn_b, w1_b, gel_b, nullptr, nullptr, 1024, 4096);
  // 8. out = x1 + g @ w2^T
  gemm_bt<2, 2><<<dim3(8, 64), 256, 0, stream>>>(gel_b, w2_b, nullptr, out, out, 4096, 1024);
}

// Round 3
// 403.326 us; speedup vs baseline: 1.4030x; 1.1481x over previous
//
#include <hip/hip_runtime.h>
#include <stdint.h>

#define D_MODEL 1024
#define NUM_HEADS 16
#define D_FF 4096
#define BB 2
#define TT 2048
#define NROWS (BB * TT)  // 4096

typedef __bf16 bf16x8 __attribute__((ext_vector_type(8)));
typedef short s16x8 __attribute__((ext_vector_type(8)));
typedef float f32x4 __attribute__((ext_vector_type(4)));

static __device__ __forceinline__ f32x4 mfma16(s16x8 a, s16x8 b, f32x4 c) {
  return __builtin_amdgcn_mfma_f32_16x16x32_bf16(
      __builtin_bit_cast(bf16x8, a), __builtin_bit_cast(bf16x8, b), c, 0, 0, 0);
}

// fp32 -> bf16 RNE
static __device__ __forceinline__ short f2b(float f) {
  union { float f; uint32_t u; } v; v.f = f;
  return (short)((v.u + 0x7FFFu + ((v.u >> 16) & 1u)) >> 16);
}

typedef __attribute__((address_space(1))) const unsigned int gu32;
typedef __attribute__((address_space(3))) unsigned int lu32;
static __device__ __forceinline__ void gload16(const short* g, short* l) {
  __builtin_amdgcn_global_load_lds((gu32*)g, (lu32*)l, 16, 0, 0);
}

// ---------------- RMSNorm: f32 [rows][1024] -> bf16 ----------------
__global__ __launch_bounds__(256) void rmsnorm_kernel(
    const float* __restrict__ x, const float* __restrict__ g, short* __restrict__ out) {
  const int row = blockIdx.x;
  const int tid = threadIdx.x;
  const float4 xv = *(const float4*)(x + (size_t)row * D_MODEL + tid * 4);
  float ss = xv.x * xv.x + xv.y * xv.y + xv.z * xv.z + xv.w * xv.w;
#pragma unroll
  for (int off = 32; off >= 1; off >>= 1) ss += __shfl_down(ss, off);
  __shared__ float part[4];
  if ((tid & 63) == 0) part[tid >> 6] = ss;
  __syncthreads();
  const float tot = part[0] + part[1] + part[2] + part[3];
  const float sc = rsqrtf(tot * (1.0f / D_MODEL) + 1e-5f);
  const float4 gv = *(const float4*)(g + tid * 4);
  short4 o;
  o.x = f2b(xv.x * sc * gv.x);
  o.y = f2b(xv.y * sc * gv.y);
  o.z = f2b(xv.z * sc * gv.z);
  o.w = f2b(xv.w * sc * gv.w);
  *(short4*)(out + (size_t)row * D_MODEL + tid * 4) = o;
}

// ---------------- f32 -> bf16 converts ----------------
__global__ __launch_bounds__(256) void cvt_kernel(
    const float* __restrict__ in, short* __restrict__ out, int n) {
  const int i = (blockIdx.x * 256 + threadIdx.x) * 8;
  if (i >= n) return;
  const float4 a = *(const float4*)(in + i);
  const float4 b = *(const float4*)(in + i + 4);
  union { short s[8]; s16x8 v; } u;
  u.s[0] = f2b(a.x); u.s[1] = f2b(a.y); u.s[2] = f2b(a.z); u.s[3] = f2b(a.w);
  u.s[4] = f2b(b.x); u.s[5] = f2b(b.y); u.s[6] = f2b(b.z); u.s[7] = f2b(b.w);
  *(s16x8*)(out + i) = u.v;
}

__global__ __launch_bounds__(256) void cvt4_kernel(
    const float* __restrict__ a, const float* __restrict__ b,
    const float* __restrict__ c, const float* __restrict__ d,
    short* __restrict__ oa, short* __restrict__ ob,
    short* __restrict__ oc, short* __restrict__ od) {
  const int gid = blockIdx.x * 256 + threadIdx.x;
  const int seg = gid >> 17;
  const int off = (gid & 131071) * 8;
  const float* in = seg == 0 ? a : seg == 1 ? b : seg == 2 ? c : d;
  short* out = seg == 0 ? oa : seg == 1 ? ob : seg == 2 ? oc : od;
  const float4 lo = *(const float4*)(in + off);
  const float4 hi = *(const float4*)(in + off + 4);
  union { short s[8]; s16x8 v; } u;
  u.s[0] = f2b(lo.x); u.s[1] = f2b(lo.y); u.s[2] = f2b(lo.z); u.s[3] = f2b(lo.w);
  u.s[4] = f2b(hi.x); u.s[5] = f2b(hi.y); u.s[6] = f2b(hi.z); u.s[7] = f2b(hi.w);
  *(s16x8*)(out + off) = u.v;
}

// ---------------- GEMM core: 2-phase double-buffered ----------------
// C[M,N] = A[M,K] @ B[N,K]^T, bf16 in, fp32 acc. BM = MFRAG*32, BN = 128.
template <int MFRAG>
__device__ __forceinline__ void gemm_core(
    const short* __restrict__ A, const short* __restrict__ Bw,
    int K, int brow, int bcol,
    short (&As)[2][MFRAG * 32][32], short (&Bs)[2][128][32],
    f32x4 (*acc)[4]) {
  const int tid = threadIdx.x;
  const int lane = tid & 63, wv = tid >> 6;
  const int l15 = lane & 15, lg = lane >> 4;
  const int wr = wv >> 1, wc = wv & 1;

  const int srow = wv * 16 + (lane >> 2);
  const int schunk = lane & 3;
  const short* Ag[MFRAG / 2];
  const short* Bg[2];
#pragma unroll
  for (int j = 0; j < MFRAG / 2; ++j)
    Ag[j] = A + (size_t)(brow + j * 64 + srow) * K + schunk * 8;
#pragma unroll
  for (int j = 0; j < 2; ++j)
    Bg[j] = Bw + (size_t)(bcol + j * 64 + srow) * K + schunk * 8;

  // prologue: stage tile 0 into buf 0
#pragma unroll
  for (int j = 0; j < MFRAG / 2; ++j)
    gload16(Ag[j], &As[0][0][0] + j * 2048 + wv * 512);
#pragma unroll
  for (int j = 0; j < 2; ++j)
    gload16(Bg[j], &Bs[0][0][0] + j * 2048 + wv * 512);

  int cur = 0;
  for (int k0 = 0; k0 < K; k0 += 32) {
    __syncthreads();  // buf[cur] staged; buf[cur^1] reads from prev iter done
    if (k0 + 32 < K) {
      const int nb = cur ^ 1, ko = k0 + 32;
#pragma unroll
      for (int j = 0; j < MFRAG / 2; ++j)
        gload16(Ag[j] + ko, &As[nb][0][0] + j * 2048 + wv * 512);
#pragma unroll
      for (int j = 0; j < 2; ++j)
        gload16(Bg[j] + ko, &Bs[nb][0][0] + j * 2048 + wv * 512);
    }
    s16x8 af[MFRAG], bfr[4];
#pragma unroll
    for (int m = 0; m < MFRAG; ++m)
      af[m] = *(const s16x8*)&As[cur][wr * (MFRAG * 16) + m * 16 + l15][lg * 8];
#pragma unroll
    for (int n = 0; n < 4; ++n)
      bfr[n] = *(const s16x8*)&Bs[cur][wc * 64 + n * 16 + l15][lg * 8];
#pragma unroll
    for (int m = 0; m < MFRAG; ++m)
#pragma unroll
      for (int n = 0; n < 4; ++n)
        acc[m][n] = mfma16(af[m], bfr[n], acc[m][n]);
    cur ^= 1;
  }
}

// MODE 0: bf16 C. MODE 2: f32 C + resid. MODE 3: bf16 gelu(C).
template <int MODE, int MFRAG>
__global__ __launch_bounds__(256) void gemm_bt(
    const short* __restrict__ A, const short* __restrict__ Bw,
    short* __restrict__ outb, float* __restrict__ outf,
    const float* __restrict__ resid, int K, int N) {
  __shared__ __align__(16) short As[2][MFRAG * 32][32];
  __shared__ __align__(16) short Bs[2][128][32];
  f32x4 acc[MFRAG][4] = {};
  const int brow = blockIdx.y * (MFRAG * 32), bcol = blockIdx.x * 128;
  gemm_core<MFRAG>(A, Bw, K, brow, bcol, As, Bs, acc);

  const int tid = threadIdx.x, lane = tid & 63;
  const int wv = tid >> 6, wr = wv >> 1, wc = wv & 1;
  const int l15 = lane & 15, lg = lane >> 4;
#pragma unroll
  for (int m = 0; m < MFRAG; ++m)
#pragma unroll
    for (int n = 0; n < 4; ++n)
#pragma unroll
      for (int r = 0; r < 4; ++r) {
        const int grow = brow + wr * (MFRAG * 16) + m * 16 + lg * 4 + r;
        const int gcol = bcol + wc * 64 + n * 16 + l15;
        const float v = acc[m][n][r];
        const size_t idx = (size_t)grow * N + gcol;
        if (MODE == 0) {
          outb[idx] = f2b(v);
        } else if (MODE == 2) {
          outf[idx] = v + resid[idx];
        } else {
          outb[idx] = f2b(0.5f * v * (1.0f + erff(v * 0.70710678118f)));
        }
      }
}

// Fused QKV. sel 0->Q (pre-scaled by 0.125), 1->K, 2->V (transposed [bh][d][t]).
__global__ __launch_bounds__(256) void gemm_qkv(
    const short* __restrict__ A, const short* __restrict__ Wq,
    const short* __restrict__ Wk, const short* __restrict__ Wv,
    short* __restrict__ qout, short* __restrict__ kout, short* __restrict__ vtout) {
  __shared__ __align__(16) short As[2][128][32];
  __shared__ __align__(16) short Bs[2][128][32];
  const int sel = blockIdx.x >> 3;
  const int bcol = (blockIdx.x & 7) * 128;
  const int brow = blockIdx.y * 128;
  const short* Bw = sel == 0 ? Wq : sel == 1 ? Wk : Wv;
  f32x4 acc[4][4] = {};
  gemm_core<4>(A, Bw, 1024, brow, bcol, As, Bs, acc);

  const int tid = threadIdx.x, lane = tid & 63;
  const int wv = tid >> 6, wr = wv >> 1, wc = wv & 1;
  const int l15 = lane & 15, lg = lane >> 4;
  short* outb = sel == 0 ? qout : kout;
#pragma unroll
  for (int m = 0; m < 4; ++m)
#pragma unroll
    for (int n = 0; n < 4; ++n)
#pragma unroll
      for (int r = 0; r < 4; ++r) {
        const int grow = brow + wr * 64 + m * 16 + lg * 4 + r;
        const int gcol = bcol + wc * 64 + n * 16 + l15;
        float v = acc[m][n][r];
        if (sel == 0) v *= 0.125f;  // fold 1/sqrt(d_k) into Q
        const short vb = f2b(v);
        if (sel < 2) {
          outb[(size_t)grow * 1024 + gcol] = vb;
        } else {
          const int bq = grow >> 11, t = grow & 2047;
          const int hh = gcol >> 6, d = gcol & 63;
          vtout[(((size_t)((bq << 4) + hh) << 6) + d) * 2048 + t] = vb;
        }
      }
}

// ---------------- Flash-style causal attention, QBLK=128 KBLK=64 ----------
// grid = (32 bh, 16 qb). All q-blocks of one bh land on one XCD (%8 heuristic);
// heavy q-blocks (high qbase) dispatch first via y-reversal.
__global__ __launch_bounds__(256) void attn_kernel(
    const short* __restrict__ qb, const short* __restrict__ kb,
    const short* __restrict__ vt, short* __restrict__ att) {
  const int bh = blockIdx.x, bq = bh >> 4, h = bh & 15;
  const int qbase = ((int)gridDim.y - 1 - (int)blockIdx.y) * 128;
  const int tid = threadIdx.x, lane = tid & 63, w = tid >> 6;
  const int l15 = lane & 15, lg = lane >> 4;

  __shared__ __align__(16) short Ks[2][64][64];
  __shared__ __align__(16) short Vs[2][64][64];
  __shared__ __align__(16) short Ps[4][32][64];

  const short* qhead = qb + (size_t)bq * 2048 * 1024 + h * 64;
  const short* khead = kb + (size_t)bq * 2048 * 1024 + h * 64;
  const short* vhead = vt + (size_t)bh * 64 * 2048;

  // Q fragments (already pre-scaled by 0.125)
  s16x8 aq[2][2];
#pragma unroll
  for (int mq = 0; mq < 2; ++mq) {
    const short* qp = qhead + (size_t)(qbase + mq * 64 + w * 16 + l15) * 1024 + lg * 8;
    aq[mq][0] = *(const s16x8*)(qp);
    aq[mq][1] = *(const s16x8*)(qp + 32);
  }

  f32x4 acc[2][4] = {};
  float mrow[2][4], lrow[2][4];
#pragma unroll
  for (int mq = 0; mq < 2; ++mq)
#pragma unroll
    for (int r = 0; r < 4; ++r) { mrow[mq][r] = -1e30f; lrow[mq][r] = 0.f; }

  // staging geometry (linear dest + pre-swizzled source chunk, read XOR swz)
  const int ssub = lane >> 3;
  const int gch = (lane & 7) ^ ssub;
  const int swz = l15 & 7;

  const int nkt = qbase / 64 + 2;

#define STAGE_KV(buf, k0)                                                     \
  {                                                                           \
    _Pragma("unroll") for (int j = 0; j < 2; ++j) {                           \
      const int row = j * 32 + w * 8 + ssub;                                  \
      gload16(khead + (size_t)((k0) + row) * 1024 + gch * 8,                  \
              &Ks[buf][0][0] + j * 2048 + w * 512);                           \
      gload16(vhead + (size_t)row * 2048 + (k0) + gch * 8,                    \
              &Vs[buf][0][0] + j * 2048 + w * 512);                           \
    }                                                                         \
  }

  STAGE_KV(0, 0);
  int cur = 0;
  for (int kt = 0; kt < nkt; ++kt) {
    const int k0 = kt * 64;
    __syncthreads();  // buf[cur] ready; prev reads of buf[cur^1] done
    if (kt + 1 < nkt) STAGE_KV(cur ^ 1, k0 + 64);

    const bool act0 = (k0 <= qbase + w * 16 + 15);  // frag mq=0 has valid cols

    // K b-fragments
    s16x8 bk[4][2];
#pragma unroll
    for (int c = 0; c < 4; ++c) {
      const int r = c * 16 + l15;
#pragma unroll
      for (int kh = 0; kh < 2; ++kh)
        bk[c][kh] = *(const s16x8*)&Ks[cur][r][((kh * 4 + lg) ^ swz) * 8];
    }

    // QK^T for both frags (scores already include 0.125)
    f32x4 s[2][4] = {};
    __builtin_amdgcn_s_setprio(1);
#pragma unroll
    for (int mq = 0; mq < 2; ++mq) {
      if (mq == 0 && !act0) continue;
#pragma unroll
      for (int c = 0; c < 4; ++c) {
        s[mq][c] = mfma16(aq[mq][0], bk[c][0], s[mq][c]);
        s[mq][c] = mfma16(aq[mq][1], bk[c][1], s[mq][c]);
      }
    }
    __builtin_amdgcn_s_setprio(0);

    // mask + online softmax (defer-max THR=8, per-lane partial l)
#pragma unroll
    for (int mq = 0; mq < 2; ++mq) {
      if (mq == 0 && !act0) continue;
      const int rbase = qbase + mq * 64 + w * 16;
      if (k0 + 63 > rbase) {
#pragma unroll
        for (int c = 0; c < 4; ++c) {
          const int kcol = k0 + c * 16 + l15;
#pragma unroll
          for (int r = 0; r < 4; ++r)
            if (kcol > rbase + lg * 4 + r) s[mq][c][r] = -1e30f;
        }
      }
      float mt[4];
#pragma unroll
      for (int r = 0; r < 4; ++r)
        mt[r] = fmaxf(fmaxf(s[mq][0][r], s[mq][1][r]), fmaxf(s[mq][2][r], s[mq][3][r]));
#pragma unroll
      for (int off = 8; off >= 1; off >>= 1)
#pragma unroll
        for (int r = 0; r < 4; ++r) mt[r] = fmaxf(mt[r], __shfl_xor(mt[r], off));
      bool need = false;
#pragma unroll
      for (int r = 0; r < 4; ++r) need = need || (mt[r] > mrow[mq][r] + 8.0f);
      if (__any(need)) {
#pragma unroll
        for (int r = 0; r < 4; ++r) {
          const float mnew = fmaxf(mrow[mq][r], mt[r]);
          const float scl = __expf(mrow[mq][r] - mnew);
          mrow[mq][r] = mnew;
          lrow[mq][r] *= scl;
#pragma unroll
          for (int df = 0; df < 4; ++df) acc[mq][df][r] *= scl;
        }
      }
#pragma unroll
      for (int c = 0; c < 4; ++c)
#pragma unroll
        for (int r = 0; r < 4; ++r) {
          const float p = __expf(s[mq][c][r] - mrow[mq][r]);
          lrow[mq][r] += p;  // per-lane partial; cross-lane reduce deferred
          const int prow = mq * 16 + lg * 4 + r;
          const int ch = c * 2 + (l15 >> 3);
          Ps[w][prow][((ch ^ (prow & 7)) << 3) + (l15 & 7)] = f2b(p);
        }
    }

    // V b-fragments
    s16x8 bv[4][2];
#pragma unroll
    for (int df = 0; df < 4; ++df) {
      const int r = df * 16 + l15;
#pragma unroll
      for (int kh = 0; kh < 2; ++kh)
        bv[df][kh] = *(const s16x8*)&Vs[cur][r][((kh * 4 + lg) ^ swz) * 8];
    }

    // PV
    __builtin_amdgcn_s_setprio(1);
#pragma unroll
    for (int mq = 0; mq < 2; ++mq) {
      if (mq == 0 && !act0) continue;
#pragma unroll
      for (int kh = 0; kh < 2; ++kh) {
        const s16x8 pa = *(const s16x8*)&Ps[w][mq * 16 + l15][((kh * 4 + lg) ^ swz) * 8];
#pragma unroll
        for (int df = 0; df < 4; ++df)
          acc[mq][df] = mfma16(pa, bv[df][kh], acc[mq][df]);
      }
    }
    __builtin_amdgcn_s_setprio(0);
    cur ^= 1;
  }

  // deferred cross-lane l reduction + output
#pragma unroll
  for (int mq = 0; mq < 2; ++mq) {
#pragma unroll
    for (int off = 8; off >= 1; off >>= 1)
#pragma unroll
      for (int r = 0; r < 4; ++r) lrow[mq][r] += __shfl_xor(lrow[mq][r], off);
    float inv[4];
#pragma unroll
    for (int r = 0; r < 4; ++r) inv[r] = 1.0f / lrow[mq][r];
#pragma unroll
    for (int df = 0; df < 4; ++df)
#pragma unroll
      for (int r = 0; r < 4; ++r) {
        const int qrow = qbase + mq * 64 + w * 16 + lg * 4 + r;
        const int d = df * 16 + l15;
        att[((size_t)(bq * 2048) + qrow) * 1024 + h * 64 + d] =
            f2b(acc[mq][df][r] * inv[r]);
      }
  }
}

// ---------------- launch ----------------
extern "C" void kernel_launch(void* const* d_in, const int* in_sizes, int n_in,
                              void* d_out, int out_size, void* d_ws, size_t ws_size,
                              hipStream_t stream) {
  const float* x  = (const float*)d_in[0];
  const float* wq = (const float*)d_in[1];
  const float* wk = (const float*)d_in[2];
  const float* wv = (const float*)d_in[3];
  const float* wo = (const float*)d_in[4];
  const float* w1 = (const float*)d_in[5];
  const float* w2 = (const float*)d_in[6];
  const float* g1 = (const float*)d_in[7];
  const float* g2 = (const float*)d_in[8];
  float* out = (float*)d_out;

  char* ws = (char*)d_ws;
  const size_t MB = 1u << 20;
  short* wq_b  = (short*)(ws + 0 * MB);
  short* wk_b  = (short*)(ws + 2 * MB);
  short* wv_b  = (short*)(ws + 4 * MB);
  short* wo_b  = (short*)(ws + 6 * MB);
  short* w1_b  = (short*)(ws + 8 * MB);
  short* w2_b  = (short*)(ws + 16 * MB);
  short* xn_b  = (short*)(ws + 24 * MB);
  short* q_b   = (short*)(ws + 32 * MB);
  short* k_b   = (short*)(ws + 40 * MB);
  short* vt_b  = (short*)(ws + 48 * MB);
  short* att_b = (short*)(ws + 56 * MB);
  short* gel_b = (short*)(ws + 32 * MB);  // aliases q/k/vt/att (dead by FFN1)

  // 1. xn = rmsnorm(x, g1)
  rmsnorm_kernel<<<NROWS, 256, 0, stream>>>(x, g1, xn_b);
  // 2. weights -> bf16
  cvt4_kernel<<<2048, 256, 0, stream>>>(wq, wk, wv, wo, wq_b, wk_b, wv_b, wo_b);
  cvt_kernel<<<2048, 256, 0, stream>>>(w1, w1_b, 1 << 22);
  cvt_kernel<<<2048, 256, 0, stream>>>(w2, w2_b, 1 << 22);
  // 3. fused QKV (Q pre-scaled, V transposed)
  gemm_qkv<<<dim3(24, 32), 256, 0, stream>>>(xn_b, wq_b, wk_b, wv_b, q_b, k_b, vt_b);
  // 4. attention
  attn_kernel<<<dim3(32, 16), 256, 0, stream>>>(q_b, k_b, vt_b, att_b);
  // 5. x1 = x + att @ wo^T  (x1 in d_out, f32)
  gemm_bt<2, 2><<<dim3(8, 64), 256, 0, stream>>>(att_b, wo_b, nullptr, out, x, 1024, 1024);
  // 6. h = rmsnorm(x1, g2)
  rmsnorm_kernel<<<NROWS, 256, 0, stream>>>(out, g2, xn_b);
  // 7. g = gelu(h @ w1^T)
  gemm_bt<3, 4><<<dim3(32, 32), 256, 0, stream>>>(xn_b, w1_b, gel_b, nullptr, nullptr, 1024, 4096);
  // 8. out = x1 + g @ w2^T
  gemm_bt<2, 2><<<dim3(8, 64), 256, 0, stream>>>(gel_b, w2_b, nullptr, out, out, 4096, 1024);
}